// Round 18
// baseline (52.562 us; speedup 1.0000x reference)
//
#include <hip/hip_runtime.h>
#include <hip/hip_bf16.h>
#include <math.h>

#define BB 32
#define RR 2000
#define CC 81
#define CM1 80
#define TROWS 64
#define NTILE 32            // tiles per batch (32 * 64 = 2048 >= 2000)
#define NTILES_TOTAL 1024   // BB * NTILE
#define CAP 28              // max stored pairs per (column, tile)
#define SCAP (NTILE * CAP)  // 896
#define NCOLS 2560          // BB * CM1

// ---------------------------------------------------------------------------
// L1 (block-specialized): 1024 compact+softmax blocks + 16,000 zero blocks.
//   compact blocks (bid < 1024): stage 64-row tile in LDS ->
//     (a) ballot-compact per class -> counts/pairs
//     (b) softmax for the tile's 64 rows from LDS (lane=class, 16 rows/wave)
//         -> dist/maxs/labels.  cls is read ONCE for both uses.
//   zero blocks (bid >= 1024): 480 float4 of dets+sv (123 MB, BW-bound).
//   The latency-bound compact+softmax chain hides under the zero stream.
// ---------------------------------------------------------------------------
__global__ __launch_bounds__(256) void compact_softmax_zero_kernel(
    const float* __restrict__ cls,   // (B, R, 81)
    float* __restrict__ dist,        // (B*R, 81)
    float* __restrict__ maxs,        // (B*R,)
    float* __restrict__ labels,      // (B*R,)
    float4* __restrict__ zbase,      // dets start: 30,720,000 floats to zero
    int* __restrict__ counts,        // (2560, NTILE)
    float2* __restrict__ pairs)      // (2560, SCAP)
{
    __shared__ float tile[CC * (TROWS + 1)];
    const int tid  = threadIdx.x;
    const int wave = tid >> 6;
    const int lane = tid & 63;

    if (blockIdx.x < NTILES_TOTAL) {
        // ---------------- compact + softmax path ----------------
        const int b   = blockIdx.x >> 5;
        const int tr  = blockIdx.x & 31;
        const int r0  = tr * TROWS;
        const int nr  = (RR - r0 < TROWS) ? (RR - r0) : TROWS;

        const float* src = cls + (size_t)(b * RR + r0) * CC;
        for (int i = tid; i < nr * CC; i += 256) {
            int rl = i / CC, c = i - rl * CC;
            tile[c * (TROWS + 1) + rl] = src[i];
        }
        __syncthreads();

        // (a) ballot-compact: wave w handles classes 1+w, 5+w, ...
        #pragma unroll 4
        for (int q = 0; q < 20; ++q) {
            const int c   = 1 + wave + 4 * q;          // classes 1..80
            const int col = b * CM1 + (c - 1);
            float s = tile[c * (TROWS + 1) + lane];
            bool valid = (lane < nr) && (s > 0.1f);
            unsigned long long mask = __ballot(valid);
            if (valid) {
                int pos = __popcll(mask & ((1ull << lane) - 1ull));
                if (pos < CAP)
                    pairs[(size_t)col * SCAP + tr * CAP + pos] =
                        make_float2(s, __int_as_float(r0 + lane));
            }
            if (lane == 0) {
                int cnt = (int)__popcll(mask);
                counts[col * NTILE + tr] = (cnt < CAP) ? cnt : CAP;
            }
        }

        // (b) softmax from LDS: wave w does local rows w*16 .. w*16+15.
        //     LDS read tile[lane*65+rl]: bank (lane+rl)%32 -> 2-way, free.
        for (int t = 0; t < 16; ++t) {
            const int rl = wave * 16 + t;
            if (rl >= nr) break;
            const int grow = b * RR + r0 + rl;

            float v0 = tile[lane * (TROWS + 1) + rl];
            float v1 = (lane < CC - 64) ? tile[(64 + lane) * (TROWS + 1) + rl]
                                        : -INFINITY;

            float m  = v0;
            int   mi = lane;
            if (v1 > m) { m = v1; mi = 64 + lane; }

            for (int off = 32; off > 0; off >>= 1) {
                float om  = __shfl_xor(m, off);
                int   omi = __shfl_xor(mi, off);
                if (om > m || (om == m && omi < mi)) { m = om; mi = omi; }
            }

            float e0 = expf(v0 - m);
            float e1 = (lane < CC - 64) ? expf(v1 - m) : 0.0f;
            float s  = e0 + e1;
            for (int off = 32; off > 0; off >>= 1) s += __shfl_xor(s, off);

            float inv = 1.0f / s;
            float* outd = dist + (size_t)grow * CC;
            outd[lane] = e0 * inv;
            if (lane < CC - 64) outd[64 + lane] = e1 * inv;
            if (lane == 0) {
                maxs[grow]   = inv;
                labels[grow] = (float)mi;
            }
        }
        return;
    }

    // ---------------- zero path ----------------
    const int zb = (blockIdx.x - NTILES_TOTAL) * 480;
    const float4 z4 = make_float4(0.0f, 0.0f, 0.0f, 0.0f);
    zbase[zb + tid] = z4;
    if (tid < 224) zbase[zb + 256 + tid] = z4;
}

// ---------------------------------------------------------------------------
// L2 (sort+decode, round-12 proven): one 128-thread block per column.
//   wave-parallel count scan (shfl_up), gather segments to LDS, bitonic
//   (register n<=64 / LDS otherwise), decode, scatter valid prefix only.
// ---------------------------------------------------------------------------
__global__ __launch_bounds__(128) void sort_decode_kernel(
    const float* __restrict__ rois,   // (B, R, 5)
    const float* __restrict__ bbox,   // (B, R, 4*C)
    const int* __restrict__ counts,   // (2560, NTILE)
    const float2* __restrict__ pairs, // (2560, SCAP)
    float* __restrict__ dets,         // (B, R, 80, 5), pre-zeroed
    float* __restrict__ sv)           // (B, R, 80), pre-zeroed
{
    __shared__ float ssc[1024];
    __shared__ int   sidx[1024];
    __shared__ int   scnt[NTILE];
    __shared__ int   spref[NTILE + 1];

    const int bj  = blockIdx.x;
    const int b   = bj / CM1;
    const int j   = bj % CM1;
    const int tid = threadIdx.x;
    const int wave = tid >> 6;
    const int lane = tid & 63;
    const int cls_col = j + 1;

    if (wave == 0) {
        int c = (lane < NTILE) ? counts[bj * NTILE + lane] : 0;
        int x = c;
        #pragma unroll
        for (int off = 1; off < NTILE; off <<= 1) {
            int v = __shfl_up(x, off);
            if (lane >= off) x += v;
        }
        if (lane < NTILE) {
            scnt[lane]  = c;
            spref[lane] = x - c;
            if (lane == NTILE - 1) spref[NTILE] = x;
        }
    }
    __syncthreads();

    const int n = spref[NTILE];
    if (n == 0) return;

    const float2* pbase = pairs + (size_t)bj * SCAP;
    for (int t = wave; t < NTILE; t += 2) {
        int cnt = scnt[t];
        for (int k = lane; k < cnt; k += 64) {
            float2 e = pbase[t * CAP + k];
            int pos = spref[t] + k;
            ssc[pos]  = e.x;
            sidx[pos] = __float_as_int(e.y);
        }
    }
    __syncthreads();

    if (n > 1) {
        if (n <= 64) {
            if (wave == 0) {
                float s  = (lane < n) ? ssc[lane]  : -INFINITY;
                int   id = (lane < n) ? sidx[lane] : 0x7FFFFFFF;
                #pragma unroll
                for (int k = 2; k <= 64; k <<= 1) {
                    #pragma unroll
                    for (int jj = k >> 1; jj > 0; jj >>= 1) {
                        float os = __shfl_xor(s, jj);
                        int   oi = __shfl_xor(id, jj);
                        bool mineFirst = (s > os) || (s == os && id < oi);
                        bool iLower = ((lane & jj) == 0);
                        bool up = ((lane & k) == 0);
                        bool keep = up ? (mineFirst == iLower)
                                       : (mineFirst != iLower);
                        if (!keep) { s = os; id = oi; }
                    }
                }
                if (lane < n) { ssc[lane] = s; sidx[lane] = id; }
            }
            __syncthreads();
        } else {
            int n2 = 1;
            while (n2 < n) n2 <<= 1;
            for (int i = n + tid; i < n2; i += 128) {
                ssc[i]  = -INFINITY;
                sidx[i] = 0x7FFFFFFF;
            }
            __syncthreads();
            for (int k = 2; k <= n2; k <<= 1) {
                for (int jj = k >> 1; jj > 0; jj >>= 1) {
                    for (int i = tid; i < n2; i += 128) {
                        int ixj = i ^ jj;
                        if (ixj > i) {
                            float si = ssc[i], sx = ssc[ixj];
                            int   ii = sidx[i], ix = sidx[ixj];
                            bool before = (si > sx) || (si == sx && ii < ix);
                            bool doswap = ((i & k) == 0) ? !before : before;
                            if (doswap) {
                                ssc[i] = sx; ssc[ixj] = si;
                                sidx[i] = ix; sidx[ixj] = ii;
                            }
                        }
                    }
                    __syncthreads();
                }
            }
        }
    }

    for (int i = tid; i < n; i += 128) {
        size_t obase = ((size_t)(b * RR + i) * CM1 + j) * 5;
        int   r = sidx[i];
        float s = ssc[i];
        const float* rp = rois + (size_t)(b * RR + r) * 5;
        float x1 = rp[1], y1 = rp[2], x2 = rp[3], y2 = rp[4];
        float w  = x2 - x1 + 1.0f;
        float h  = y2 - y1 + 1.0f;
        float cx = x1 + 0.5f * w;
        float cy = y1 + 0.5f * h;
        const float* dp = bbox + (size_t)(b * RR + r) * (4 * CC) + 4 * cls_col;
        float dx = dp[0] * 0.1f, dy = dp[1] * 0.1f;
        float dw = dp[2] * 0.2f, dh = dp[3] * 0.2f;
        float pcx = dx * w + cx;
        float pcy = dy * h + cy;
        float pw  = expf(dw) * w;
        float ph  = expf(dh) * h;
        dets[obase + 0] = fmaxf(pcx - 0.5f * pw, 0.0f);
        dets[obase + 1] = fmaxf(pcy - 0.5f * ph, 0.0f);
        dets[obase + 2] = fmaxf(pcx + 0.5f * pw - 1.0f, 0.0f);
        dets[obase + 3] = fmaxf(pcy + 0.5f * ph - 1.0f, 0.0f);
        dets[obase + 4] = s;
        sv[(size_t)(b * RR + i) * CM1 + j] = 1.0f;
    }
}

extern "C" void kernel_launch(void* const* d_in, const int* in_sizes, int n_in,
                              void* d_out, int out_size, void* d_ws, size_t ws_size,
                              hipStream_t stream) {
    const float* rois = (const float*)d_in[0];   // B*R*5
    const float* cls  = (const float*)d_in[1];   // B*R*81
    const float* bbox = (const float*)d_in[2];   // B*R*324

    float* out = (float*)d_out;
    const size_t sv_off   = (size_t)BB * RR * CM1 * 5;         // 25,600,000
    const size_t dist_off = sv_off + (size_t)BB * RR * CM1;    // 30,720,000
    const size_t maxs_off = dist_off + (size_t)BB * RR * CC;   // 35,904,000
    const size_t lab_off  = maxs_off + (size_t)BB * RR;        // 35,968,000

    float* dets   = out;
    float* sv     = out + sv_off;
    float* dist   = out + dist_off;
    float* maxs   = out + maxs_off;
    float* labels = out + lab_off;

    // Workspace: counts (2560*32 ints) + pairs (2560*896 float2)
    int*    counts = (int*)d_ws;
    float2* pairs  = (float2*)((char*)d_ws + (size_t)NCOLS * NTILE * sizeof(int));

    // L1: compact+softmax (latency) hides under the dets+sv zero-fill (BW);
    //     cls read exactly once.
    compact_softmax_zero_kernel<<<NTILES_TOTAL + (BB * RR) / 4, 256, 0, stream>>>(
        cls, dist, maxs, labels, (float4*)dets, counts, pairs);

    // L2: sort+decode (round-12 structure).
    sort_decode_kernel<<<NCOLS, 128, 0, stream>>>(
        rois, bbox, counts, pairs, dets, sv);
}

// Round 19
// 45.284 us; speedup vs baseline: 1.1607x; 1.1607x over previous
//
#include <hip/hip_runtime.h>
#include <hip/hip_bf16.h>
#include <math.h>

#define BB 32
#define RR 2000
#define CC 81
#define CM1 80
#define TROWS 64
#define NTILE 32            // tiles per batch (32 * 64 = 2048 >= 2000)
#define NTILES_TOTAL 1024   // BB * NTILE
#define CAP 28              // max stored pairs per (column, tile)
#define SCAP (NTILE * CAP)  // 896
#define NCOLS 2560          // BB * CM1

// ---------------------------------------------------------------------------
// L1 (block-specialized, r12 structure): 1024 compact + 16,000 prep blocks.
//   compact (bid < 1024): stage 64-row tile in LDS, ballot-compact per class
//     -> counts/pairs. NEW: prefetch the rois rows + the exact bbox float4
//     each valid entry needs (keep-alive asm, loads only) to warm L3 for K2.
//   prep (bid >= 1024): zero 480 float4 of dets+sv, 4 waves x 1 row softmax
//     -> dist/maxs/labels. BW-bound (~27 us floor).
// ---------------------------------------------------------------------------
__global__ __launch_bounds__(256) void fused1_kernel(
    const float* __restrict__ cls,   // (B, R, 81)
    const float* __restrict__ rois,  // (B, R, 5)
    const float* __restrict__ bbox,  // (B, R, 324)
    float* __restrict__ dist,        // (B*R, 81)
    float* __restrict__ maxs,        // (B*R,)
    float* __restrict__ labels,      // (B*R,)
    float4* __restrict__ zbase,      // dets start: 30,720,000 floats to zero
    int* __restrict__ counts,        // (2560, NTILE)
    float2* __restrict__ pairs)      // (2560, SCAP)
{
    __shared__ float tile[CC * (TROWS + 1)];
    const int tid  = threadIdx.x;
    const int wave = tid >> 6;
    const int lane = tid & 63;

    if (blockIdx.x < NTILES_TOTAL) {
        // ---------------- compact path ----------------
        const int b   = blockIdx.x >> 5;
        const int tr  = blockIdx.x & 31;
        const int r0  = tr * TROWS;
        const int nr  = (RR - r0 < TROWS) ? (RR - r0) : TROWS;

        const float* src = cls + (size_t)(b * RR + r0) * CC;
        for (int i = tid; i < nr * CC; i += 256) {
            int rl = i / CC, c = i - rl * CC;
            tile[c * (TROWS + 1) + rl] = src[i];
        }

        // rois prefetch: one row per lane (wave 0) -> warms L2/L3 for K2.
        if (wave == 0 && lane < nr) {
            const float4 rv = *(const float4*)(rois +
                (size_t)(b * RR + r0 + lane) * 5 + 1);
            asm volatile("" :: "v"(rv.x), "v"(rv.y), "v"(rv.z), "v"(rv.w));
        }
        __syncthreads();

        #pragma unroll 4
        for (int q = 0; q < 20; ++q) {
            const int c   = 1 + wave + 4 * q;          // classes 1..80
            const int col = b * CM1 + (c - 1);
            float s = tile[c * (TROWS + 1) + lane];
            bool valid = (lane < nr) && (s > 0.1f);
            unsigned long long mask = __ballot(valid);
            if (valid) {
                int pos = __popcll(mask & ((1ull << lane) - 1ull));
                if (pos < CAP)
                    pairs[(size_t)col * SCAP + tr * CAP + pos] =
                        make_float2(s, __int_as_float(r0 + lane));
                // bbox prefetch for this exact (row, class) -> warm L3.
                const float4 d4 = *(const float4*)(bbox +
                    (size_t)(b * RR + r0 + lane) * (4 * CC) + 4 * c);
                asm volatile("" :: "v"(d4.x), "v"(d4.y), "v"(d4.z), "v"(d4.w));
            }
            if (lane == 0) {
                int cnt = (int)__popcll(mask);
                counts[col * NTILE + tr] = (cnt < CAP) ? cnt : CAP;
            }
        }
        return;
    }

    // ---------------- prep path (r12 proven) ----------------
    const int pb = blockIdx.x - NTILES_TOTAL;   // 0..15999

    const float4 z4 = make_float4(0.0f, 0.0f, 0.0f, 0.0f);
    const int zb = pb * 480;
    zbase[zb + tid] = z4;
    if (tid < 224) zbase[zb + 256 + tid] = z4;

    const int row = pb * 4 + wave;

    const float* in = cls + (size_t)row * CC;
    float v0 = in[lane];
    float v1 = (lane < CC - 64) ? in[64 + lane] : -INFINITY;

    float m  = v0;
    int   mi = lane;
    if (v1 > m) { m = v1; mi = 64 + lane; }

    for (int off = 32; off > 0; off >>= 1) {
        float om  = __shfl_xor(m, off);
        int   omi = __shfl_xor(mi, off);
        if (om > m || (om == m && omi < mi)) { m = om; mi = omi; }
    }

    float e0 = expf(v0 - m);
    float e1 = (lane < CC - 64) ? expf(v1 - m) : 0.0f;
    float s  = e0 + e1;
    for (int off = 32; off > 0; off >>= 1) s += __shfl_xor(s, off);

    float inv = 1.0f / s;
    float* out = dist + (size_t)row * CC;
    out[lane] = e0 * inv;
    if (lane < CC - 64) out[64 + lane] = e1 * inv;
    if (lane == 0) {
        maxs[row]   = inv;
        labels[row] = (float)mi;
    }
}

// ---------------------------------------------------------------------------
// K2 (sort+decode): one 128-thread block per column.
//   n <= 128 (vast majority): both waves scan counts in registers, gather
//     element g = wave*64+lane direct to registers (shfl binary search),
//     wave0 sorts desc / wave1 asc (register bitonic), one LDS exchange at
//     distance 64 + 6 shfl clean steps -> full descending sort with ONE
//     barrier. Decode straight from registers.
//   n > 128 (rare): r12's LDS bitonic fallback.
// ---------------------------------------------------------------------------
__global__ __launch_bounds__(128) void sort_decode_kernel(
    const float* __restrict__ rois,   // (B, R, 5)
    const float* __restrict__ bbox,   // (B, R, 4*C)
    const int* __restrict__ counts,   // (2560, NTILE)
    const float2* __restrict__ pairs, // (2560, SCAP)
    float* __restrict__ dets,         // (B, R, 80, 5), pre-zeroed
    float* __restrict__ sv)           // (B, R, 80), pre-zeroed
{
    __shared__ float ssc[1024];
    __shared__ int   sidx[1024];
    __shared__ int   scnt[NTILE];
    __shared__ int   spref[NTILE + 1];

    const int bj  = blockIdx.x;
    const int b   = bj / CM1;
    const int j   = bj % CM1;
    const int tid = threadIdx.x;
    const int wave = tid >> 6;
    const int lane = tid & 63;
    const int cls_col = j + 1;

    // Both waves load + scan counts in registers (no barrier needed).
    int c = (lane < NTILE) ? counts[bj * NTILE + lane] : 0;
    int x = c;
    #pragma unroll
    for (int off = 1; off < NTILE; off <<= 1) {
        int v = __shfl_up(x, off);
        if (lane >= off) x += v;
    }
    const int e = x - c;                      // exclusive prefix (lanes < 32)
    const int n = __shfl(x, NTILE - 1);       // total
    if (n == 0) return;

    const float2* pbase = pairs + (size_t)bj * SCAP;

    if (n <= 128) {
        const int g = (wave << 6) | lane;     // my element index 0..127

        // find my tile via 5-step shfl binary search over the prefix
        int lo = 0;
        #pragma unroll
        for (int st = 16; st > 0; st >>= 1) {
            int p = lo + st;
            int v = __shfl(e, (p < NTILE) ? p : 0);
            if (p < NTILE && v <= g) lo = p;
        }
        int base = __shfl(e, lo);

        float s; int id;
        if (g < n) {
            float2 pr = pbase[lo * CAP + (g - base)];
            s  = pr.x;
            id = __float_as_int(pr.y);
        } else {
            s  = -INFINITY;
            id = 0x7FFFFFFF;
        }

        // per-wave register bitonic: wave0 descending, wave1 ascending
        const bool asc = (wave == 1);
        #pragma unroll
        for (int k = 2; k <= 64; k <<= 1) {
            #pragma unroll
            for (int jj = k >> 1; jj > 0; jj >>= 1) {
                float os = __shfl_xor(s, jj);
                int   oi = __shfl_xor(id, jj);
                bool mineFirst = (s > os) || (s == os && id < oi);
                if (asc) mineFirst = !mineFirst;
                bool iLower = ((lane & jj) == 0);
                bool up = ((lane & k) == 0);
                bool keep = up ? (mineFirst == iLower) : (mineFirst != iLower);
                if (!keep) { s = os; id = oi; }
            }
        }

        // bitonic merge: exchange at distance 64 via LDS (one barrier)
        ssc[tid]  = s;
        sidx[tid] = id;
        __syncthreads();
        {
            float os = ssc[tid ^ 64];
            int   oi = sidx[tid ^ 64];
            bool mineFirst = (s > os) || (s == os && id < oi);
            bool iLower = (wave == 0);
            if (mineFirst != iLower) { s = os; id = oi; }
        }
        // descending clean, intra-wave (shfl only)
        #pragma unroll
        for (int jj = 32; jj > 0; jj >>= 1) {
            float os = __shfl_xor(s, jj);
            int   oi = __shfl_xor(id, jj);
            bool mineFirst = (s > os) || (s == os && id < oi);
            bool iLower = ((lane & jj) == 0);
            if (mineFirst != iLower) { s = os; id = oi; }
        }

        // decode element g straight from registers
        if (g < n) {
            size_t obase = ((size_t)(b * RR + g) * CM1 + j) * 5;
            int   r = id;
            const float* rp = rois + (size_t)(b * RR + r) * 5;
            float x1 = rp[1], y1 = rp[2], x2 = rp[3], y2 = rp[4];
            float w  = x2 - x1 + 1.0f;
            float h  = y2 - y1 + 1.0f;
            float cx = x1 + 0.5f * w;
            float cy = y1 + 0.5f * h;
            const float* dp = bbox + (size_t)(b * RR + r) * (4 * CC) + 4 * cls_col;
            float dx = dp[0] * 0.1f, dy = dp[1] * 0.1f;
            float dw = dp[2] * 0.2f, dh = dp[3] * 0.2f;
            float pcx = dx * w + cx;
            float pcy = dy * h + cy;
            float pw  = expf(dw) * w;
            float ph  = expf(dh) * h;
            dets[obase + 0] = fmaxf(pcx - 0.5f * pw, 0.0f);
            dets[obase + 1] = fmaxf(pcy - 0.5f * ph, 0.0f);
            dets[obase + 2] = fmaxf(pcx + 0.5f * pw - 1.0f, 0.0f);
            dets[obase + 3] = fmaxf(pcy + 0.5f * ph - 1.0f, 0.0f);
            dets[obase + 4] = s;
            sv[(size_t)(b * RR + g) * CM1 + j] = 1.0f;
        }
        return;
    }

    // ---------------- n > 128: r12 LDS-bitonic fallback ----------------
    if (wave == 0 && lane < NTILE) {
        scnt[lane]  = c;
        spref[lane] = e;
        if (lane == NTILE - 1) spref[NTILE] = n;
    }
    __syncthreads();

    for (int t = wave; t < NTILE; t += 2) {
        int cnt = scnt[t];
        for (int k = lane; k < cnt; k += 64) {
            float2 pe = pbase[t * CAP + k];
            int pos = spref[t] + k;
            ssc[pos]  = pe.x;
            sidx[pos] = __float_as_int(pe.y);
        }
    }
    __syncthreads();

    int n2 = 1;
    while (n2 < n) n2 <<= 1;
    for (int i = n + tid; i < n2; i += 128) {
        ssc[i]  = -INFINITY;
        sidx[i] = 0x7FFFFFFF;
    }
    __syncthreads();
    for (int k = 2; k <= n2; k <<= 1) {
        for (int jj = k >> 1; jj > 0; jj >>= 1) {
            for (int i = tid; i < n2; i += 128) {
                int ixj = i ^ jj;
                if (ixj > i) {
                    float si = ssc[i], sx = ssc[ixj];
                    int   ii = sidx[i], ix = sidx[ixj];
                    bool before = (si > sx) || (si == sx && ii < ix);
                    bool doswap = ((i & k) == 0) ? !before : before;
                    if (doswap) {
                        ssc[i] = sx; ssc[ixj] = si;
                        sidx[i] = ix; sidx[ixj] = ii;
                    }
                }
            }
            __syncthreads();
        }
    }

    for (int i = tid; i < n; i += 128) {
        size_t obase = ((size_t)(b * RR + i) * CM1 + j) * 5;
        int   r = sidx[i];
        float s = ssc[i];
        const float* rp = rois + (size_t)(b * RR + r) * 5;
        float x1 = rp[1], y1 = rp[2], x2 = rp[3], y2 = rp[4];
        float w  = x2 - x1 + 1.0f;
        float h  = y2 - y1 + 1.0f;
        float cx = x1 + 0.5f * w;
        float cy = y1 + 0.5f * h;
        const float* dp = bbox + (size_t)(b * RR + r) * (4 * CC) + 4 * cls_col;
        float dx = dp[0] * 0.1f, dy = dp[1] * 0.1f;
        float dw = dp[2] * 0.2f, dh = dp[3] * 0.2f;
        float pcx = dx * w + cx;
        float pcy = dy * h + cy;
        float pw  = expf(dw) * w;
        float ph  = expf(dh) * h;
        dets[obase + 0] = fmaxf(pcx - 0.5f * pw, 0.0f);
        dets[obase + 1] = fmaxf(pcy - 0.5f * ph, 0.0f);
        dets[obase + 2] = fmaxf(pcx + 0.5f * pw - 1.0f, 0.0f);
        dets[obase + 3] = fmaxf(pcy + 0.5f * ph - 1.0f, 0.0f);
        dets[obase + 4] = s;
        sv[(size_t)(b * RR + i) * CM1 + j] = 1.0f;
    }
}

extern "C" void kernel_launch(void* const* d_in, const int* in_sizes, int n_in,
                              void* d_out, int out_size, void* d_ws, size_t ws_size,
                              hipStream_t stream) {
    const float* rois = (const float*)d_in[0];   // B*R*5
    const float* cls  = (const float*)d_in[1];   // B*R*81
    const float* bbox = (const float*)d_in[2];   // B*R*324

    float* out = (float*)d_out;
    const size_t sv_off   = (size_t)BB * RR * CM1 * 5;         // 25,600,000
    const size_t dist_off = sv_off + (size_t)BB * RR * CM1;    // 30,720,000
    const size_t maxs_off = dist_off + (size_t)BB * RR * CC;   // 35,904,000
    const size_t lab_off  = maxs_off + (size_t)BB * RR;        // 35,968,000

    float* dets   = out;
    float* sv     = out + sv_off;
    float* dist   = out + dist_off;
    float* maxs   = out + maxs_off;
    float* labels = out + lab_off;

    // Workspace: counts (2560*32 ints) + pairs (2560*896 float2)
    int*    counts = (int*)d_ws;
    float2* pairs  = (float2*)((char*)d_ws + (size_t)NCOLS * NTILE * sizeof(int));

    fused1_kernel<<<NTILES_TOTAL + (BB * RR) / 4, 256, 0, stream>>>(
        cls, rois, bbox, dist, maxs, labels, (float4*)dets, counts, pairs);

    sort_decode_kernel<<<NCOLS, 128, 0, stream>>>(
        rois, bbox, counts, pairs, dets, sv);
}